// Round 9
// baseline (271.278 us; speedup 1.0000x reference)
//
#include <hip/hip_runtime.h>

// Problem constants (B, N, D fixed by the reference)
#define B_ 32
#define N_ 4096
#define D_ 256
#define K_ 2048            // max(1, int(N * (1 - 0.5)))

// rank_top tiling (r6-proven geometry, applied to the compacted top-K set)
#define TJSPLIT 16                  // j-chunks per batch (128 keys each)
#define TEPT 8                      // i-elements per thread (contiguous)
#define TJSLICE (K_ / TJSPLIT)      // 128 j-keys staged in LDS per block

// ---------------------------------------------------------------------------
// Kernel 1: compute the 64-bit sort key for every (b, i); zero rankSlot and
// meanAccum (ws is poisoned each launch).
// Key = (orderable(f32 noisy) << 32) | ~index  -> larger key == earlier in
// descending top-k order, ties broken by LOWER index (matches lax.top_k).
// Bit-identical to the round-0 (passing) kernel's key computation.
// ---------------------------------------------------------------------------
__global__ __launch_bounds__(256) void key_kernel(
    const float* __restrict__ attn, const float* __restrict__ noise,
    unsigned long long* __restrict__ keys,
    unsigned long long* __restrict__ rankSlot64,
    float* __restrict__ meanAccum) {
  const int t = blockIdx.x * 256 + threadIdx.x;   // 0 .. B*N-1
  float u = noise[t];
  float a = attn[t];
  float x = __fadd_rn(u, 1e-10f);              // u + 1e-10
  float l1 = (float)log((double)x);            // ~correctly-rounded f32 log
  float inner = __fadd_rn(-l1, 1e-10f);        // -log(u+1e-10) + 1e-10
  float g = -(float)log((double)inner);        // gumbel
  float noisy = __fadd_rn(a, __fmul_rn(0.1f, g));  // attn + 0.1*g (no FMA)
  unsigned int fb = __float_as_uint(noisy);
  fb = (fb & 0x80000000u) ? ~fb : (fb | 0x80000000u);  // orderable f32
  int i = t & (N_ - 1);
  keys[t] = ((unsigned long long)fb << 32) | (unsigned int)(~i);
  if (t < B_ * K_ / 4) rankSlot64[t] = 0ull;   // zero u16 slot-rank buffer
  if (t < B_ * D_) meanAccum[t] = 0.0f;
}

// ---------------------------------------------------------------------------
// Kernel 2: EXACT top-K partition per batch (radix-select, hi-32 bits).
// One block per batch, 256 threads, 16 elements each (idx = e*256 + tid).
// 4 byte-passes: histogram the current-active elements' byte, find the
// threshold byte t where the descending cumulative count crosses the budget;
// byte > t  -> permanently selected, byte < t -> rejected, byte == t -> stays
// active for the next pass. After 4 passes the actives share the exact hi-32
// threshold; remaining budget R is filled by the R largest low-words
// (lo = ~i, all distinct -> exact, matches full-key descending order).
// Writes selFlag[b][i] and compacts the K selected full keys (unordered).
// Work: ~4096 LDS-atomic hist ops + tiny refinements -> ~2-4 us wall
// (32 blocks concurrent). Worst-case (massive hi-32 ties) degrades to the
// tie loop but stays exact.
// ---------------------------------------------------------------------------
__global__ __launch_bounds__(256) void select_kernel(
    const unsigned long long* __restrict__ keys,
    unsigned long long* __restrict__ topKeys,
    unsigned char* __restrict__ selFlag) {
  const int b = blockIdx.x;
  const int tid = threadIdx.x;
  const unsigned long long* __restrict__ bk = keys + (size_t)b * N_;

  unsigned long long kreg[16];
#pragma unroll
  for (int e = 0; e < 16; ++e) kreg[e] = bk[e * 256 + tid];

  __shared__ unsigned int hist[256];
  __shared__ unsigned int sParam[2];     // [0] = t byte, [1] = A (count > t)
  __shared__ unsigned int tieLo[N_];     // 16 KiB worst case
  __shared__ unsigned int tieCnt;
  __shared__ unsigned int topCnt;

  unsigned int selMask = 0u;             // bit e: permanently selected
  unsigned int actMask = 0xFFFFu;        // bit e: still active
  unsigned int budget = K_;

  if (tid == 0) topCnt = 0u;

  for (int p = 0; p < 4; ++p) {
    const int shift = 24 - 8 * p;
    hist[tid] = 0u;
    if (tid == 0) tieCnt = 0u;
    __syncthreads();
#pragma unroll
    for (int e = 0; e < 16; ++e) {
      if (actMask & (1u << e)) {
        unsigned int h = (unsigned int)(kreg[e] >> 32);
        atomicAdd(&hist[(h >> shift) & 255u], 1u);
      }
    }
    __syncthreads();
    {
      // suffix sum s_v = sum_{u >= v} hist[u]; unique crossing of budget
      unsigned int sv = 0u;
      for (int u = tid; u < 256; ++u) sv += hist[u];
      unsigned int svn = sv - hist[tid];        // suffix from tid+1
      if (sv >= budget && svn < budget) {
        sParam[0] = (unsigned int)tid;          // t
        sParam[1] = svn;                        // A = # elements with byte > t
      }
    }
    __syncthreads();
    const unsigned int t = sParam[0];
    const unsigned int A = sParam[1];
    budget -= A;                                // uniform update
#pragma unroll
    for (int e = 0; e < 16; ++e) {
      if (actMask & (1u << e)) {
        unsigned int byteV = ((unsigned int)(kreg[e] >> 32) >> shift) & 255u;
        if (byteV > t) { selMask |= (1u << e); actMask &= ~(1u << e); }
        else if (byteV < t) { actMask &= ~(1u << e); }
      }
    }
    __syncthreads();
  }

  // tie resolution: actives share the exact hi-32 threshold; pick the
  // 'budget' largest low-words (distinct ~i values)
#pragma unroll
  for (int e = 0; e < 16; ++e) {
    if (actMask & (1u << e)) {
      unsigned int slot = atomicAdd(&tieCnt, 1u);
      tieLo[slot] = (unsigned int)kreg[e];
    }
  }
  __syncthreads();
  const unsigned int E = tieCnt;
  const unsigned int R = budget;
#pragma unroll
  for (int e = 0; e < 16; ++e) {
    if (actMask & (1u << e)) {
      unsigned int lo = (unsigned int)kreg[e];
      unsigned int c = 0u;
      for (unsigned int k2 = 0u; k2 < E; ++k2) c += (tieLo[k2] > lo);
      if (c < R) selMask |= (1u << e);
    }
  }

  // write flags + compact selected keys (unordered slots)
#pragma unroll
  for (int e = 0; e < 16; ++e) {
    const int idx = e * 256 + tid;
    const unsigned int sel = (selMask >> e) & 1u;
    selFlag[(size_t)b * N_ + idx] = (unsigned char)sel;
    if (sel) {
      unsigned int slot = atomicAdd(&topCnt, 1u);
      topKeys[(size_t)b * K_ + slot] = kreg[e];
    }
  }
}

// ---------------------------------------------------------------------------
// Kernel 3: all-pairs rank WITHIN the compacted top-K set (r6 structure).
// 4x fewer compares than the full-N rank (134M vs 537M pairs); rank within
// the top set by full u64 descending == final output position.
// Block (jc, b): 2048 i-keys (TEPT=8 contiguous per thread, registers) vs a
// 128-key j-slice staged in LDS (broadcast ds_read_b128, conflict-free).
// Merge: 8 u16 partials packed into 2 u64 atomicAdds (rank < 2048 -> no
// field carry). 512 blocks.
// ---------------------------------------------------------------------------
__global__ __launch_bounds__(256) void rank_top_kernel(
    const unsigned long long* __restrict__ topKeys,
    unsigned long long* __restrict__ rankSlot64) {
  const int b = blockIdx.y;
  const int jc = blockIdx.x;               // 0..TJSPLIT-1
  __shared__ __align__(16) unsigned long long lk[TJSLICE];  // 1 KiB

  const unsigned long long* __restrict__ bk = topKeys + (size_t)b * K_;
  if (threadIdx.x < TJSLICE) lk[threadIdx.x] = bk[jc * TJSLICE + threadIdx.x];

  const int ibase = threadIdx.x * TEPT;
  unsigned long long ki[TEPT];
  const ulonglong2* __restrict__ gi2 = (const ulonglong2*)(bk + ibase);
#pragma unroll
  for (int e2 = 0; e2 < TEPT / 2; ++e2) {
    ulonglong2 v = gi2[e2];
    ki[2 * e2] = v.x;
    ki[2 * e2 + 1] = v.y;
  }
  __syncthreads();

  const ulonglong2* lk2 = (const ulonglong2*)lk;
  unsigned int rk[TEPT] = {0u, 0u, 0u, 0u, 0u, 0u, 0u, 0u};
#pragma unroll 4
  for (int j = 0; j < TJSLICE / 2; ++j) {
    ulonglong2 v = lk2[j];                 // broadcast read, conflict-free
#pragma unroll
    for (int e = 0; e < TEPT; ++e) {
      rk[e] += (v.x > ki[e]);
      rk[e] += (v.y > ki[e]);
    }
  }

  unsigned long long p0 =
      (unsigned long long)rk[0] | ((unsigned long long)rk[1] << 16) |
      ((unsigned long long)rk[2] << 32) | ((unsigned long long)rk[3] << 48);
  unsigned long long p1 =
      (unsigned long long)rk[4] | ((unsigned long long)rk[5] << 16) |
      ((unsigned long long)rk[6] << 32) | ((unsigned long long)rk[7] << 48);
  const size_t q = ((size_t)b * K_ + ibase) >> 2;   // u64 index (ibase%4==0)
  atomicAdd(&rankSlot64[q], p0);
  atomicAdd(&rankSlot64[q + 1], p1);
}

// ---------------------------------------------------------------------------
// Kernel 4: pruned-row mean accumulation via selFlag complement.
// Grid (32, B), 128 i's per block; threads < 128 collect pruned indices into
// an LDS list; 4 x 64-lane wave-groups gather rows (1 KB coalesced) + reduce.
// ---------------------------------------------------------------------------
__global__ __launch_bounds__(256) void mean_kernel(
    const unsigned char* __restrict__ selFlag, const float* __restrict__ seq,
    float* __restrict__ meanAccum) {
  const int b = blockIdx.y;
  const int ibase = blockIdx.x * 128;       // grid.x = 32
  __shared__ int plist[128];
  __shared__ int pcount;
  if (threadIdx.x == 0) pcount = 0;
  __syncthreads();
  if (threadIdx.x < 128) {
    const int i = ibase + threadIdx.x;
    if (selFlag[(size_t)b * N_ + i] == 0) {
      int slot = atomicAdd(&pcount, 1);
      plist[slot] = i;
    }
  }
  __syncthreads();
  const int cnt = pcount;

  const int dv = threadIdx.x & 63;        // float4 column 0..63
  const int sub = threadIdx.x >> 6;       // wave-group 0..3
  float4 acc = make_float4(0.f, 0.f, 0.f, 0.f);
  for (int r = sub; r < cnt; r += 4) {
    const float4* row = (const float4*)(seq + ((size_t)b * N_ + plist[r]) * D_);
    float4 v = row[dv];
    acc.x += v.x; acc.y += v.y; acc.z += v.z; acc.w += v.w;
  }

  __shared__ float4 red[4][64];
  red[sub][dv] = acc;
  __syncthreads();
  if (sub == 0) {
    float4 s0 = red[0][dv], s1 = red[1][dv], s2 = red[2][dv], s3 = red[3][dv];
    float sx = s0.x + s1.x + s2.x + s3.x;
    float sy = s0.y + s1.y + s2.y + s3.y;
    float sz = s0.z + s1.z + s2.z + s3.z;
    float sw = s0.w + s1.w + s2.w + s3.w;
    float* dst = meanAccum + b * D_ + dv * 4;
    atomicAdd(dst + 0, sx);
    atomicAdd(dst + 1, sy);
    atomicAdd(dst + 2, sz);
    atomicAdd(dst + 3, sw);
  }
}

// ---------------------------------------------------------------------------
// Kernel 5: scatter output via compacted slots.
// Grid (16, B), 128 slots per block; 4 x 64-lane wave-groups. For each slot:
// i decoded from the key's low word (~i), rank from rankSlot16 (both wave-
// uniform -> scalar loads). out[b][rank][:] = seq[b][i][:] + 0.05 * mean,
// 1 KB coalesced read AND write per row; ranks are a permutation of [0,K).
// ---------------------------------------------------------------------------
__global__ __launch_bounds__(256) void out_kernel(
    const unsigned long long* __restrict__ topKeys,
    const unsigned short* __restrict__ rankSlot16,
    const float* __restrict__ seq,
    const float* __restrict__ meanAccum, float* __restrict__ out) {
  const int b = blockIdx.y;
  const int sbase = blockIdx.x * 128;       // grid.x = 16
  const int dv = threadIdx.x & 63;          // float4 column 0..63
  const int sub = threadIdx.x >> 6;         // wave-group 0..3

  float4 m = ((const float4*)(meanAccum + b * D_))[dv];
  const float s = 0.05f * (1.0f / 2048.0f);  // count = 2048 (+1e-10 is sub-ulp)
  float4 mix;
  mix.x = m.x * s; mix.y = m.y * s; mix.z = m.z * s; mix.w = m.w * s;

  for (int r = sub; r < 128; r += 4) {
    const int slot = sbase + r;
    unsigned long long key = topKeys[(size_t)b * K_ + slot];
    const int i = (int)(~(unsigned int)key) & (N_ - 1);   // lo = ~i
    const unsigned int rank = rankSlot16[(size_t)b * K_ + slot];
    const float4* row = (const float4*)(seq + ((size_t)b * N_ + i) * D_);
    float4 v = row[dv];
    float4 o;
    o.x = v.x + mix.x; o.y = v.y + mix.y; o.z = v.z + mix.z; o.w = v.w + mix.w;
    ((float4*)(out + ((size_t)b * K_ + rank) * D_))[dv] = o;
  }
}

// ---------------------------------------------------------------------------
extern "C" void kernel_launch(void* const* d_in, const int* in_sizes, int n_in,
                              void* d_out, int out_size, void* d_ws, size_t ws_size,
                              hipStream_t stream) {
  const float* seq  = (const float*)d_in[0];
  const float* attn = (const float*)d_in[1];
  const float* nois = (const float*)d_in[2];
  float* out = (float*)d_out;

  // workspace layout (~1.82 MiB total)
  float* meanAccum = (float*)d_ws;                                      // 32 KiB
  unsigned long long* keys =
      (unsigned long long*)((char*)d_ws + (size_t)B_ * D_ * 4);         // 1 MiB
  unsigned long long* topKeys =
      (unsigned long long*)((char*)keys + (size_t)B_ * N_ * 8);         // 512 KiB
  unsigned long long* rankSlot64 =
      (unsigned long long*)((char*)topKeys + (size_t)B_ * K_ * 8);      // 128 KiB (u16[B*K])
  unsigned short* rankSlot16 = (unsigned short*)rankSlot64;
  unsigned char* selFlag =
      (unsigned char*)((char*)rankSlot64 + (size_t)B_ * K_ * 2);        // 128 KiB

  key_kernel<<<(B_ * N_) / 256, 256, 0, stream>>>(attn, nois, keys, rankSlot64, meanAccum);
  select_kernel<<<B_, 256, 0, stream>>>(keys, topKeys, selFlag);
  rank_top_kernel<<<dim3(TJSPLIT, B_), 256, 0, stream>>>(topKeys, rankSlot64);
  mean_kernel<<<dim3(32, B_), 256, 0, stream>>>(selFlag, seq, meanAccum);
  out_kernel<<<dim3(16, B_), 256, 0, stream>>>(topKeys, rankSlot16, seq, meanAccum, out);
}